// Round 6
// baseline (159.222 us; speedup 1.0000x reference)
//
#include <hip/hip_runtime.h>

#define D 8
#define NE 4
#define NS 3
#define NI 5
#define LN_EPS 1e-5f

// ---------------------------------------------------------------------------
// Setup kernel: C[s][n][d] = bproj[s][d] + sum_ij Bmat[s][n][i][j]*Wproj[s][d][i*8+j]
// ---------------------------------------------------------------------------
__global__ void precompute_C_kernel(const float* __restrict__ Bmat,
                                    const float* __restrict__ Wproj,
                                    const float* __restrict__ bproj,
                                    float* __restrict__ C) {
    int idx = threadIdx.x;
    if (idx >= NS * NE * D) return;
    int s = idx / (NE * D);
    int rem = idx % (NE * D);
    int n = rem / D;
    int d = rem % D;
    const float* bm = Bmat + ((size_t)s * NE + n) * 64;
    const float* wp = Wproj + ((size_t)s * D + d) * 64;
    float acc = bproj[s * D + d];
    #pragma unroll
    for (int k = 0; k < 64; ++k) acc += bm[k] * wp[k];
    C[idx] = acc;
}

__device__ __forceinline__ float fast_tanh(float x) {
    float e = __expf(2.f * x);
    return 1.f - 2.f * __builtin_amdgcn_rcpf(e + 1.f);
}

// lane <-> lane^1 exchange via DPP quad_perm [1,0,3,2] (full-rate VALU)
__device__ __forceinline__ float xor1f(float x) {
    int i = __builtin_bit_cast(int, x);
    i = __builtin_amdgcn_mov_dpp(i, 0xB1, 0xF, 0xF, true);
    return __builtin_bit_cast(float, i);
}

__device__ __forceinline__ float4 ld4(const float* p) {
    return *reinterpret_cast<const float4*>(p);
}

// ---------------------------------------------------------------------------
// Main kernel: TWO lanes per row (lane parity p owns d-half {4p..4p+3}).
// Doubles waves/SIMD (2 -> 4) and halves per-lane live registers (~100 < 128
// so the allocator neither spills nor shuffles through AGPRs). Cross-lane
// halves exchanged with DPP xor-1. Register arrays are stored lane-permuted
// (tA = my-half cols, tB = other-half) so ALL indexing is compile-time.
// The memory clobber in the inner loop blocks LICM from hoisting ~70 regs of
// weight loads (round-5 spill failure mode); weights re-read from hot L1.
// ---------------------------------------------------------------------------
__global__ __launch_bounds__(256, 4) void whisp_kernel(
    const float* __restrict__ cl, const float* __restrict__ cd,
    const float* __restrict__ re_log, const float* __restrict__ mach,
    const float* __restrict__ alpha, const float* __restrict__ u,
    const float* __restrict__ We, const float* __restrict__ be,
    const float* __restrict__ Wproj,
    const float* __restrict__ Wr1, const float* __restrict__ br1,
    const float* __restrict__ Wr2, const float* __restrict__ br2,
    const float* __restrict__ ln_g, const float* __restrict__ ln_b,
    const float* __restrict__ Wout, const float* __restrict__ bout,
    const float* __restrict__ fg, const float* __restrict__ fb,
    const float* __restrict__ Wcst, const float* __restrict__ bcst,
    const float* __restrict__ Wcl, const float* __restrict__ bcl,
    const float* __restrict__ Cpre,
    float* __restrict__ out, int B)
{
    __shared__ float souts[128 * 19];   // 9728 B

    const int tid = threadIdx.x;
    const int p   = tid & 1;            // lane parity: which d-half I own
    const int rl  = tid >> 1;           // row within block (0..127)
    const int row0 = blockIdx.x * 128 + rl;
    const bool active = (row0 < B);
    const int row = active ? row0 : (B - 1);
    const int d0  = p * 4;              // my d-offset
    const int d0o = d0 ^ 4;             // other half's d-offset

    // ---- per-row inputs (uu full: needed for t) ----
    float uu[8];
    {
        const float4* up = reinterpret_cast<const float4*>(u + (size_t)row * D);
        float4 u0 = up[0], u1 = up[1];
        uu[0]=u0.x; uu[1]=u0.y; uu[2]=u0.z; uu[3]=u0.w;
        uu[4]=u1.x; uu[5]=u1.y; uu[6]=u1.z; uu[7]=u1.w;
    }
    float xs[NE] = { cl[row], cd[row], re_log[row], mach[row] };
    float al = alpha[row];

    // ---- embedding: E[n][dd] for my d-half ----
    float E[NE][4];
    #pragma unroll
    for (int n = 0; n < NE; ++n) {
        float4 wa = ld4(We + n * 16 + d0 * 2);       // (d0,d0+1) x (w0,w1)
        float4 wb = ld4(We + n * 16 + d0 * 2 + 4);   // (d0+2,d0+3)
        float4 bv = ld4(be + n * D + d0);
        E[n][0] = fast_tanh(fmaf(wa.x, xs[n], fmaf(wa.y, al, bv.x)));
        E[n][1] = fast_tanh(fmaf(wa.z, xs[n], fmaf(wa.w, al, bv.y)));
        E[n][2] = fast_tanh(fmaf(wb.x, xs[n], fmaf(wb.y, al, bv.z)));
        E[n][3] = fast_tanh(fmaf(wb.z, xs[n], fmaf(wb.w, al, bv.w)));
    }

    // LN params for my d-half (invariant across stages)
    float lngv[4], lnbv[4];
    {
        float4 g = ld4(ln_g + d0), b = ld4(ln_b + d0);
        lngv[0]=g.x; lngv[1]=g.y; lngv[2]=g.z; lngv[3]=g.w;
        lnbv[0]=b.x; lnbv[1]=b.y; lnbv[2]=b.z; lnbv[3]=b.w;
    }

    // ---- outer stages ----
    #pragma unroll 1
    for (int s = 0; s < NS; ++s) {
        const float* Wp  = Wproj + (size_t)s * 512;
        const float* W1  = Wr1 + s * 64;
        const float* B1p = br1 + s * 8;
        const float* W2  = Wr2 + s * 32;
        const float* B2p = br2 + s * 4;
        const float* Cs  = Cpre + s * 32;

        // t for my d-rows, columns permuted: tA = my-half i, tB = other-half i
        float tA[4][4], tB[4][4];
        #pragma unroll
        for (int dd = 0; dd < 4; ++dd) {
            #pragma unroll
            for (int k = 0; k < 4; ++k) {
                const float* wA = Wp + (d0 + dd) * 64 + (d0 + k) * 8;
                const float* wB = Wp + (d0 + dd) * 64 + (d0o + k) * 8;
                float4 a0v = ld4(wA), a1v = ld4(wA + 4);
                float4 b0v = ld4(wB), b1v = ld4(wB + 4);
                float a0 = uu[0] * a0v.x, a1 = uu[1] * a0v.y;
                a0 = fmaf(uu[2], a0v.z, a0); a1 = fmaf(uu[3], a0v.w, a1);
                a0 = fmaf(uu[4], a1v.x, a0); a1 = fmaf(uu[5], a1v.y, a1);
                a0 = fmaf(uu[6], a1v.z, a0); a1 = fmaf(uu[7], a1v.w, a1);
                tA[dd][k] = a0 + a1;
                float c0 = uu[0] * b0v.x, c1 = uu[1] * b0v.y;
                c0 = fmaf(uu[2], b0v.z, c0); c1 = fmaf(uu[3], b0v.w, c1);
                c0 = fmaf(uu[4], b1v.x, c0); c1 = fmaf(uu[5], b1v.y, c1);
                c0 = fmaf(uu[6], b1v.z, c0); c1 = fmaf(uu[7], b1v.w, c1);
                tB[dd][k] = c0 + c1;
            }
        }

        #pragma unroll 1
        for (int it = 0; it < NI; ++it) {
            asm volatile("" ::: "memory");   // keep weight loads inside loop

            // exchange E halves
            float Eo[NE][4];
            #pragma unroll
            for (int n = 0; n < NE; ++n)
                #pragma unroll
                for (int k = 0; k < 4; ++k)
                    Eo[n][k] = xor1f(E[n][k]);

            // H[n][dd] = C + sum_full_i E*t   (my d-half)
            float H[NE][4];
            #pragma unroll
            for (int n = 0; n < NE; ++n) {
                float4 cv = ld4(Cs + n * D + d0);
                float cc[4] = { cv.x, cv.y, cv.z, cv.w };
                #pragma unroll
                for (int dd = 0; dd < 4; ++dd) {
                    float a0 = fmaf(E[n][0], tA[dd][0], cc[dd]);
                    float a1 = E[n][1] * tA[dd][1];
                    a0 = fmaf(E[n][2], tA[dd][2], a0);
                    a1 = fmaf(E[n][3], tA[dd][3], a1);
                    a0 = fmaf(Eo[n][0], tB[dd][0], a0);
                    a1 = fmaf(Eo[n][1], tB[dd][1], a1);
                    a0 = fmaf(Eo[n][2], tB[dd][2], a0);
                    a1 = fmaf(Eo[n][3], tB[dd][3], a1);
                    H[n][dd] = a0 + a1;
                }
            }

            float4 b1q = ld4(B1p + d0);
            float b1a[4] = { b1q.x, b1q.y, b1q.z, b1q.w };
            float4 b2q = ld4(B2p);
            float b2a[4] = { b2q.x, b2q.y, b2q.z, b2q.w };

            // routing softmax per expert n
            float sm[NE][NE];
            #pragma unroll
            for (int n = 0; n < NE; ++n) {
                float Ho[4];
                #pragma unroll
                for (int k = 0; k < 4; ++k) Ho[k] = xor1f(H[n][k]);
                float r[4];
                #pragma unroll
                for (int dd = 0; dd < 4; ++dd) {
                    const float* w1r = W1 + (d0 + dd) * 8;
                    float4 wa = ld4(w1r + d0);    // my-half k cols
                    float4 wb = ld4(w1r + d0o);   // other-half k cols
                    float a0 = fmaf(H[n][0], wa.x, b1a[dd]);
                    float a1 = H[n][1] * wa.y;
                    a0 = fmaf(H[n][2], wa.z, a0);
                    a1 = fmaf(H[n][3], wa.w, a1);
                    a0 = fmaf(Ho[0], wb.x, a0);
                    a1 = fmaf(Ho[1], wb.y, a1);
                    a0 = fmaf(Ho[2], wb.z, a0);
                    a1 = fmaf(Ho[3], wb.w, a1);
                    r[dd] = fmaxf(a0 + a1, 0.f);
                }
                float lgp[4];
                #pragma unroll
                for (int e = 0; e < NE; ++e) {
                    float4 w2v = ld4(W2 + e * 8 + d0);
                    float a0 = r[0] * w2v.x;
                    float a1 = r[1] * w2v.y;
                    a0 = fmaf(r[2], w2v.z, a0);
                    a1 = fmaf(r[3], w2v.w, a1);
                    lgp[e] = a0 + a1;
                }
                float lg0 = lgp[0] + xor1f(lgp[0]) + b2a[0];
                float lg1 = lgp[1] + xor1f(lgp[1]) + b2a[1];
                float lg2 = lgp[2] + xor1f(lgp[2]) + b2a[2];
                float lg3 = lgp[3] + xor1f(lgp[3]) + b2a[3];
                float mx = fmaxf(fmaxf(lg0, lg1), fmaxf(lg2, lg3));
                float e0 = __expf(lg0 - mx), e1 = __expf(lg1 - mx);
                float e2 = __expf(lg2 - mx), e3 = __expf(lg3 - mx);
                float inv = __builtin_amdgcn_rcpf((e0 + e1) + (e2 + e3));
                sm[n][0] = e0 * inv; sm[n][1] = e1 * inv;
                sm[n][2] = e2 * inv; sm[n][3] = e3 * inv;
            }

            // E += mix (all local: H stored by d-half)
            #pragma unroll
            for (int n = 0; n < NE; ++n) {
                #pragma unroll
                for (int dd = 0; dd < 4; ++dd) {
                    float a0 = fmaf(sm[n][0], H[0][dd], E[n][dd]);
                    float a1 = sm[n][1] * H[1][dd];
                    a0 = fmaf(sm[n][2], H[2][dd], a0);
                    a1 = fmaf(sm[n][3], H[3][dd], a1);
                    E[n][dd] = a0 + a1;
                }
            }
        }

        // post-stage LayerNorm per expert (cross-lane sums via DPP)
        #pragma unroll
        for (int n = 0; n < NE; ++n) {
            float sl = (E[n][0] + E[n][1]) + (E[n][2] + E[n][3]);
            float m = (sl + xor1f(sl)) * 0.125f;
            float c0 = E[n][0] - m, c1 = E[n][1] - m;
            float c2 = E[n][2] - m, c3 = E[n][3] - m;
            float vl = fmaf(c0, c0, c1 * c1) + fmaf(c2, c2, c3 * c3);
            float v = (vl + xor1f(vl)) * 0.125f;
            float inv = __builtin_amdgcn_rsqf(v + LN_EPS);
            E[n][0] = fmaf(c0 * inv, lngv[0], lnbv[0]);
            E[n][1] = fmaf(c1 * inv, lngv[1], lnbv[1]);
            E[n][2] = fmaf(c2 * inv, lngv[2], lnbv[2]);
            E[n][3] = fmaf(c3 * inv, lngv[3], lnbv[3]);
        }
    }

    // ---- final mixing: partial logits over my d-half, reduce via DPP ----
    float w0, w1, w2, w3;
    {
        float lgo[NE];
        #pragma unroll
        for (int e = 0; e < NE; ++e) {
            float a0 = 0.f, a1 = 0.f;
            #pragma unroll
            for (int n = 0; n < NE; ++n) {
                float4 wv = ld4(Wout + e * 32 + n * D + d0);
                a0 = fmaf(E[n][0], wv.x, a0);
                a1 = fmaf(E[n][1], wv.y, a1);
                a0 = fmaf(E[n][2], wv.z, a0);
                a1 = fmaf(E[n][3], wv.w, a1);
            }
            float part = a0 + a1;
            lgo[e] = part + xor1f(part) + bout[e];
        }
        float mx = fmaxf(fmaxf(lgo[0], lgo[1]), fmaxf(lgo[2], lgo[3]));
        w0 = __expf(lgo[0] - mx); w1 = __expf(lgo[1] - mx);
        w2 = __expf(lgo[2] - mx); w3 = __expf(lgo[3] - mx);
        float winv = __builtin_amdgcn_rcpf((w0 + w1) + (w2 + w3));
        w0 *= winv; w1 *= winv; w2 *= winv; w3 *= winv;
    }

    // z (my d-half) + final LN via DPP
    float z[4];
    #pragma unroll
    for (int dd = 0; dd < 4; ++dd) {
        float a0 = w0 * E[0][dd];
        float a1 = w1 * E[1][dd];
        a0 = fmaf(w2, E[2][dd], a0);
        a1 = fmaf(w3, E[3][dd], a1);
        z[dd] = a0 + a1;
    }
    {
        float sl = (z[0] + z[1]) + (z[2] + z[3]);
        float zm = (sl + xor1f(sl)) * 0.125f;
        float c0 = z[0] - zm, c1 = z[1] - zm, c2 = z[2] - zm, c3 = z[3] - zm;
        float vl = fmaf(c0, c0, c1 * c1) + fmaf(c2, c2, c3 * c3);
        float zv = (vl + xor1f(vl)) * 0.125f;
        float zinv = __builtin_amdgcn_rsqf(zv + LN_EPS);
        float4 g = ld4(fg + d0), b = ld4(fb + d0);
        z[0] = fmaf(c0 * zinv, g.x, b.x);
        z[1] = fmaf(c1 * zinv, g.y, b.y);
        z[2] = fmaf(c2 * zinv, g.z, b.z);
        z[3] = fmaf(c3 * zinv, g.w, b.w);
    }

    // heads: partial over my d-half, DPP-reduce, lane writes its k-parity
    #pragma unroll
    for (int k = 0; k < 18; ++k) {
        float4 wv = ld4(Wcst + k * D + d0);
        float a0 = z[0] * wv.x;
        float a1 = z[1] * wv.y;
        a0 = fmaf(z[2], wv.z, a0);
        a1 = fmaf(z[3], wv.w, a1);
        float part = a0 + a1;
        float full = part + xor1f(part) + bcst[k];
        if (active && ((k & 1) == p)) souts[rl * 19 + k] = full;
    }
    {
        float4 wv = ld4(Wcl + d0);
        float a0 = z[0] * wv.x;
        float a1 = z[1] * wv.y;
        a0 = fmaf(z[2], wv.z, a0);
        a1 = fmaf(z[3], wv.w, a1);
        float part = a0 + a1;
        float full = part + xor1f(part) + bcl[0];
        if (active && (p == 0)) souts[rl * 19 + 18] = full;
    }

    __syncthreads();

    // coalesced writeback of this block's 128x19 outputs
    const int base = blockIdx.x * 128;
    int nrows = B - base;
    if (nrows > 128) nrows = 128;
    if (nrows > 0) {
        const int cnt = nrows * 19;
        for (int i = tid; i < cnt; i += 256)
            out[(size_t)base * 19 + i] = souts[i];
    }
}

extern "C" void kernel_launch(void* const* d_in, const int* in_sizes, int n_in,
                              void* d_out, int out_size, void* d_ws, size_t ws_size,
                              hipStream_t stream) {
    const float* cl     = (const float*)d_in[0];
    const float* cd     = (const float*)d_in[1];
    const float* re_log = (const float*)d_in[2];
    const float* mach   = (const float*)d_in[3];
    const float* alpha  = (const float*)d_in[4];
    const float* u      = (const float*)d_in[5];
    const float* We     = (const float*)d_in[6];
    const float* be     = (const float*)d_in[7];
    const float* Bmat   = (const float*)d_in[8];
    const float* Wproj  = (const float*)d_in[9];
    const float* bproj  = (const float*)d_in[10];
    const float* Wr1    = (const float*)d_in[11];
    const float* br1    = (const float*)d_in[12];
    const float* Wr2    = (const float*)d_in[13];
    const float* br2    = (const float*)d_in[14];
    const float* ln_g   = (const float*)d_in[15];
    const float* ln_b   = (const float*)d_in[16];
    const float* Wout   = (const float*)d_in[17];
    const float* bout   = (const float*)d_in[18];
    const float* fg     = (const float*)d_in[19];
    const float* fb     = (const float*)d_in[20];
    const float* Wcst   = (const float*)d_in[21];
    const float* bcst   = (const float*)d_in[22];
    const float* Wcl    = (const float*)d_in[23];
    const float* bcl    = (const float*)d_in[24];

    float* Cpre = (float*)d_ws;   // 96 floats
    const int B = in_sizes[0];

    hipLaunchKernelGGL(precompute_C_kernel, dim3(1), dim3(128), 0, stream,
                       Bmat, Wproj, bproj, Cpre);

    const int blocks = (B + 127) / 128;   // 128 rows per 256-thread block
    hipLaunchKernelGGL(whisp_kernel, dim3(blocks), dim3(256), 0, stream,
                       cl, cd, re_log, mach, alpha, u, We, be, Wproj,
                       Wr1, br1, Wr2, br2, ln_g, ln_b, Wout, bout, fg, fb,
                       Wcst, bcst, Wcl, bcl, Cpre, (float*)d_out, B);
}

// Round 7
// 91.523 us; speedup vs baseline: 1.7397x; 1.7397x over previous
//
#include <hip/hip_runtime.h>

#define D 8
#define NE 4
#define NS 3
#define NI 5
#define LN_EPS 1e-5f

// weights-in-LDS float offsets (all 16B aligned)
#define OFF_W1 0      // NS*64  = 192
#define OFF_W2 192    // NS*32  = 96
#define OFF_B1 288    // NS*8   = 24
#define OFF_B2 312    // NS*4   = 12
#define OFF_C  324    // NS*32  = 96
#define OFF_WP 420    // NS*512 = 1536
#define WLDS_SIZE 1956

// ---------------------------------------------------------------------------
// Setup kernel: C[s][n][d] = bproj[s][d] + sum_ij Bmat[s][n][i][j]*Wproj[s][d][i*8+j]
// ---------------------------------------------------------------------------
__global__ void precompute_C_kernel(const float* __restrict__ Bmat,
                                    const float* __restrict__ Wproj,
                                    const float* __restrict__ bproj,
                                    float* __restrict__ C) {
    int idx = threadIdx.x;
    if (idx >= NS * NE * D) return;
    int s = idx / (NE * D);
    int rem = idx % (NE * D);
    int n = rem / D;
    int d = rem % D;
    const float* bm = Bmat + ((size_t)s * NE + n) * 64;
    const float* wp = Wproj + ((size_t)s * D + d) * 64;
    float acc = bproj[s * D + d];
    #pragma unroll
    for (int k = 0; k < 64; ++k) acc += bm[k] * wp[k];
    C[idx] = acc;
}

__device__ __forceinline__ float fast_tanh(float x) {
    float e = __expf(2.f * x);
    return 1.f - 2.f * __builtin_amdgcn_rcpf(e + 1.f);
}

// lane <-> lane^1 exchange via DPP quad_perm [1,0,3,2] (full-rate VALU)
__device__ __forceinline__ float xor1f(float x) {
    int i = __builtin_bit_cast(int, x);
    i = __builtin_amdgcn_mov_dpp(i, 0xB1, 0xF, 0xF, true);
    return __builtin_bit_cast(float, i);
}

__device__ __forceinline__ float4 ld4(const float* p) {
    return *reinterpret_cast<const float4*>(p);
}

// ---------------------------------------------------------------------------
// Main kernel: TWO lanes per row (lane parity p owns d-half {4p..4p+3}).
// 262144 threads -> 4 waves/SIMD; per-lane live set ~118 regs (< 128).
// Stage weights live in LDS (broadcast ds_read_b128, conflict-free).
// LICM of the ~70-float weight loads is blocked by an OPAQUE-ZERO added to
// the LDS base each iteration (asm "+v" on an int) — unlike a memory
// clobber (round-6 failure: de-SROA'd arrays -> 265MB scratch), this keeps
// E/tA/tB/H fully register-promoted.
// ---------------------------------------------------------------------------
__global__ __launch_bounds__(256, 4) void whisp_kernel(
    const float* __restrict__ cl, const float* __restrict__ cd,
    const float* __restrict__ re_log, const float* __restrict__ mach,
    const float* __restrict__ alpha, const float* __restrict__ u,
    const float* __restrict__ We, const float* __restrict__ be,
    const float* __restrict__ Wproj,
    const float* __restrict__ Wr1, const float* __restrict__ br1,
    const float* __restrict__ Wr2, const float* __restrict__ br2,
    const float* __restrict__ ln_g, const float* __restrict__ ln_b,
    const float* __restrict__ Wout, const float* __restrict__ bout,
    const float* __restrict__ fg, const float* __restrict__ fb,
    const float* __restrict__ Wcst, const float* __restrict__ bcst,
    const float* __restrict__ Wcl, const float* __restrict__ bcl,
    const float* __restrict__ Cpre,
    float* __restrict__ out, int B)
{
    __shared__ __align__(16) float wlds[WLDS_SIZE];   // 7824 B
    __shared__ float souts[128 * 19];                 // 9728 B

    const int tid = threadIdx.x;
    const int p   = tid & 1;
    const int rl  = tid >> 1;
    const int row0 = blockIdx.x * 128 + rl;
    const bool active = (row0 < B);
    const int row = active ? row0 : (B - 1);
    const int d0  = p * 4;
    const int d0o = d0 ^ 4;

    // ---- stage loop weights into LDS (once per block) ----
    for (int i = tid; i < 192;  i += 256) wlds[OFF_W1 + i] = Wr1[i];
    for (int i = tid; i < 96;   i += 256) wlds[OFF_W2 + i] = Wr2[i];
    for (int i = tid; i < 24;   i += 256) wlds[OFF_B1 + i] = br1[i];
    for (int i = tid; i < 12;   i += 256) wlds[OFF_B2 + i] = br2[i];
    for (int i = tid; i < 96;   i += 256) wlds[OFF_C + i]  = Cpre[i];
    for (int i = tid; i < 1536; i += 256) wlds[OFF_WP + i] = Wproj[i];

    // ---- per-row inputs ----
    float uu[8];
    {
        const float4* up = reinterpret_cast<const float4*>(u + (size_t)row * D);
        float4 u0 = up[0], u1 = up[1];
        uu[0]=u0.x; uu[1]=u0.y; uu[2]=u0.z; uu[3]=u0.w;
        uu[4]=u1.x; uu[5]=u1.y; uu[6]=u1.z; uu[7]=u1.w;
    }
    float xs[NE] = { cl[row], cd[row], re_log[row], mach[row] };
    float al = alpha[row];

    // ---- embedding: E[n][dd] for my d-half ----
    float E[NE][4];
    #pragma unroll
    for (int n = 0; n < NE; ++n) {
        float4 wa = ld4(We + n * 16 + d0 * 2);
        float4 wb = ld4(We + n * 16 + d0 * 2 + 4);
        float4 bv = ld4(be + n * D + d0);
        E[n][0] = fast_tanh(fmaf(wa.x, xs[n], fmaf(wa.y, al, bv.x)));
        E[n][1] = fast_tanh(fmaf(wa.z, xs[n], fmaf(wa.w, al, bv.y)));
        E[n][2] = fast_tanh(fmaf(wb.x, xs[n], fmaf(wb.y, al, bv.z)));
        E[n][3] = fast_tanh(fmaf(wb.z, xs[n], fmaf(wb.w, al, bv.w)));
    }

    // LN params for my d-half (kernel-invariant)
    float lngv[4], lnbv[4];
    {
        float4 g = ld4(ln_g + d0), b = ld4(ln_b + d0);
        lngv[0]=g.x; lngv[1]=g.y; lngv[2]=g.z; lngv[3]=g.w;
        lnbv[0]=b.x; lnbv[1]=b.y; lnbv[2]=b.z; lnbv[3]=b.w;
    }

    __syncthreads();   // wlds ready

    int zero = 0;      // opaque 0, renewed每 inner iteration

    // ---- outer stages ----
    #pragma unroll 1
    for (int s = 0; s < NS; ++s) {
        // t for my d-rows (full i), from LDS Wproj; once per stage
        const float* Wp = wlds + OFF_WP + s * 512;
        float tA[4][4], tB[4][4];
        #pragma unroll
        for (int dd = 0; dd < 4; ++dd) {
            #pragma unroll
            for (int k = 0; k < 4; ++k) {
                const float* wA = Wp + (d0 + dd) * 64 + (d0 + k) * 8;
                const float* wB = Wp + (d0 + dd) * 64 + (d0o + k) * 8;
                float4 a0v = ld4(wA), a1v = ld4(wA + 4);
                float4 b0v = ld4(wB), b1v = ld4(wB + 4);
                float a0 = uu[0] * a0v.x, a1 = uu[1] * a0v.y;
                a0 = fmaf(uu[2], a0v.z, a0); a1 = fmaf(uu[3], a0v.w, a1);
                a0 = fmaf(uu[4], a1v.x, a0); a1 = fmaf(uu[5], a1v.y, a1);
                a0 = fmaf(uu[6], a1v.z, a0); a1 = fmaf(uu[7], a1v.w, a1);
                tA[dd][k] = a0 + a1;
                float c0 = uu[0] * b0v.x, c1 = uu[1] * b0v.y;
                c0 = fmaf(uu[2], b0v.z, c0); c1 = fmaf(uu[3], b0v.w, c1);
                c0 = fmaf(uu[4], b1v.x, c0); c1 = fmaf(uu[5], b1v.y, c1);
                c0 = fmaf(uu[6], b1v.z, c0); c1 = fmaf(uu[7], b1v.w, c1);
                tB[dd][k] = c0 + c1;
            }
        }

        for (int it = 0; it < NI; ++it) {
            // opaque zero: blocks LICM of the LDS weight loads ONLY
            asm volatile("" : "+v"(zero));
            const float* W1z = wlds + OFF_W1 + s * 64 + zero;
            const float* W2z = wlds + OFF_W2 + s * 32 + zero;
            const float* B1z = wlds + OFF_B1 + s * 8  + zero;
            const float* B2z = wlds + OFF_B2 + s * 4  + zero;
            const float* Cz  = wlds + OFF_C  + s * 32 + zero;

            // H[n][dd] = C + E*tA + Eo*tB  (Eo transient per n)
            float H[NE][4];
            #pragma unroll
            for (int n = 0; n < NE; ++n) {
                float Eo0 = xor1f(E[n][0]), Eo1 = xor1f(E[n][1]);
                float Eo2 = xor1f(E[n][2]), Eo3 = xor1f(E[n][3]);
                float4 cv = ld4(Cz + n * D + d0);
                float cc[4] = { cv.x, cv.y, cv.z, cv.w };
                #pragma unroll
                for (int dd = 0; dd < 4; ++dd) {
                    float a0 = fmaf(E[n][0], tA[dd][0], cc[dd]);
                    float a1 = E[n][1] * tA[dd][1];
                    a0 = fmaf(E[n][2], tA[dd][2], a0);
                    a1 = fmaf(E[n][3], tA[dd][3], a1);
                    a0 = fmaf(Eo0, tB[dd][0], a0);
                    a1 = fmaf(Eo1, tB[dd][1], a1);
                    a0 = fmaf(Eo2, tB[dd][2], a0);
                    a1 = fmaf(Eo3, tB[dd][3], a1);
                    H[n][dd] = a0 + a1;
                }
            }

            float4 b1q = ld4(B1z + d0);
            float b1a[4] = { b1q.x, b1q.y, b1q.z, b1q.w };
            float4 b2q = ld4(B2z);
            float b2a[4] = { b2q.x, b2q.y, b2q.z, b2q.w };

            // routing softmax per expert n
            float sm[NE][NE];
            #pragma unroll
            for (int n = 0; n < NE; ++n) {
                float Ho0 = xor1f(H[n][0]), Ho1 = xor1f(H[n][1]);
                float Ho2 = xor1f(H[n][2]), Ho3 = xor1f(H[n][3]);
                float r[4];
                #pragma unroll
                for (int dd = 0; dd < 4; ++dd) {
                    const float* w1r = W1z + (d0 + dd) * 8;
                    float4 wa = ld4(w1r + d0);
                    float4 wb = ld4(w1r + d0o);
                    float a0 = fmaf(H[n][0], wa.x, b1a[dd]);
                    float a1 = H[n][1] * wa.y;
                    a0 = fmaf(H[n][2], wa.z, a0);
                    a1 = fmaf(H[n][3], wa.w, a1);
                    a0 = fmaf(Ho0, wb.x, a0);
                    a1 = fmaf(Ho1, wb.y, a1);
                    a0 = fmaf(Ho2, wb.z, a0);
                    a1 = fmaf(Ho3, wb.w, a1);
                    r[dd] = fmaxf(a0 + a1, 0.f);
                }
                float lgp[4];
                #pragma unroll
                for (int e = 0; e < NE; ++e) {
                    float4 w2v = ld4(W2z + e * 8 + d0);
                    float a0 = r[0] * w2v.x;
                    float a1 = r[1] * w2v.y;
                    a0 = fmaf(r[2], w2v.z, a0);
                    a1 = fmaf(r[3], w2v.w, a1);
                    lgp[e] = a0 + a1;
                }
                float lg0 = lgp[0] + xor1f(lgp[0]) + b2a[0];
                float lg1 = lgp[1] + xor1f(lgp[1]) + b2a[1];
                float lg2 = lgp[2] + xor1f(lgp[2]) + b2a[2];
                float lg3 = lgp[3] + xor1f(lgp[3]) + b2a[3];
                float mx = fmaxf(fmaxf(lg0, lg1), fmaxf(lg2, lg3));
                float e0 = __expf(lg0 - mx), e1 = __expf(lg1 - mx);
                float e2 = __expf(lg2 - mx), e3 = __expf(lg3 - mx);
                float inv = __builtin_amdgcn_rcpf((e0 + e1) + (e2 + e3));
                sm[n][0] = e0 * inv; sm[n][1] = e1 * inv;
                sm[n][2] = e2 * inv; sm[n][3] = e3 * inv;
            }

            // E += mix (H stored by d-half: all local)
            #pragma unroll
            for (int n = 0; n < NE; ++n) {
                #pragma unroll
                for (int dd = 0; dd < 4; ++dd) {
                    float a0 = fmaf(sm[n][0], H[0][dd], E[n][dd]);
                    float a1 = sm[n][1] * H[1][dd];
                    a0 = fmaf(sm[n][2], H[2][dd], a0);
                    a1 = fmaf(sm[n][3], H[3][dd], a1);
                    E[n][dd] = a0 + a1;
                }
            }
        }

        // post-stage LayerNorm (cross-lane sums via DPP)
        #pragma unroll
        for (int n = 0; n < NE; ++n) {
            float sl = (E[n][0] + E[n][1]) + (E[n][2] + E[n][3]);
            float m = (sl + xor1f(sl)) * 0.125f;
            float c0 = E[n][0] - m, c1 = E[n][1] - m;
            float c2 = E[n][2] - m, c3 = E[n][3] - m;
            float vl = fmaf(c0, c0, c1 * c1) + fmaf(c2, c2, c3 * c3);
            float v = (vl + xor1f(vl)) * 0.125f;
            float inv = __builtin_amdgcn_rsqf(v + LN_EPS);
            E[n][0] = fmaf(c0 * inv, lngv[0], lnbv[0]);
            E[n][1] = fmaf(c1 * inv, lngv[1], lnbv[1]);
            E[n][2] = fmaf(c2 * inv, lngv[2], lnbv[2]);
            E[n][3] = fmaf(c3 * inv, lngv[3], lnbv[3]);
        }
    }

    // ---- final mixing (weights from global; one-time, post-loop) ----
    float w0, w1, w2, w3;
    {
        float lgo[NE];
        #pragma unroll
        for (int e = 0; e < NE; ++e) {
            float a0 = 0.f, a1 = 0.f;
            #pragma unroll
            for (int n = 0; n < NE; ++n) {
                float4 wv = ld4(Wout + e * 32 + n * D + d0);
                a0 = fmaf(E[n][0], wv.x, a0);
                a1 = fmaf(E[n][1], wv.y, a1);
                a0 = fmaf(E[n][2], wv.z, a0);
                a1 = fmaf(E[n][3], wv.w, a1);
            }
            float part = a0 + a1;
            lgo[e] = part + xor1f(part) + bout[e];
        }
        float mx = fmaxf(fmaxf(lgo[0], lgo[1]), fmaxf(lgo[2], lgo[3]));
        w0 = __expf(lgo[0] - mx); w1 = __expf(lgo[1] - mx);
        w2 = __expf(lgo[2] - mx); w3 = __expf(lgo[3] - mx);
        float winv = __builtin_amdgcn_rcpf((w0 + w1) + (w2 + w3));
        w0 *= winv; w1 *= winv; w2 *= winv; w3 *= winv;
    }

    float z[4];
    #pragma unroll
    for (int dd = 0; dd < 4; ++dd) {
        float a0 = w0 * E[0][dd];
        float a1 = w1 * E[1][dd];
        a0 = fmaf(w2, E[2][dd], a0);
        a1 = fmaf(w3, E[3][dd], a1);
        z[dd] = a0 + a1;
    }
    {
        float sl = (z[0] + z[1]) + (z[2] + z[3]);
        float zm = (sl + xor1f(sl)) * 0.125f;
        float c0 = z[0] - zm, c1 = z[1] - zm, c2 = z[2] - zm, c3 = z[3] - zm;
        float vl = fmaf(c0, c0, c1 * c1) + fmaf(c2, c2, c3 * c3);
        float zv = (vl + xor1f(vl)) * 0.125f;
        float zinv = __builtin_amdgcn_rsqf(zv + LN_EPS);
        float4 g = ld4(fg + d0), b = ld4(fb + d0);
        z[0] = fmaf(c0 * zinv, g.x, b.x);
        z[1] = fmaf(c1 * zinv, g.y, b.y);
        z[2] = fmaf(c2 * zinv, g.z, b.z);
        z[3] = fmaf(c3 * zinv, g.w, b.w);
    }

    // heads: partial over my d-half, DPP-reduce, lane writes its k-parity
    #pragma unroll
    for (int k = 0; k < 18; ++k) {
        float4 wv = ld4(Wcst + k * D + d0);
        float a0 = z[0] * wv.x;
        float a1 = z[1] * wv.y;
        a0 = fmaf(z[2], wv.z, a0);
        a1 = fmaf(z[3], wv.w, a1);
        float part = a0 + a1;
        float full = part + xor1f(part) + bcst[k];
        if (active && ((k & 1) == p)) souts[rl * 19 + k] = full;
    }
    {
        float4 wv = ld4(Wcl + d0);
        float a0 = z[0] * wv.x;
        float a1 = z[1] * wv.y;
        a0 = fmaf(z[2], wv.z, a0);
        a1 = fmaf(z[3], wv.w, a1);
        float part = a0 + a1;
        float full = part + xor1f(part) + bcl[0];
        if (active && (p == 0)) souts[rl * 19 + 18] = full;
    }

    __syncthreads();

    // coalesced writeback of this block's 128x19 outputs
    const int base = blockIdx.x * 128;
    int nrows = B - base;
    if (nrows > 128) nrows = 128;
    if (nrows > 0) {
        const int cnt = nrows * 19;
        for (int i = tid; i < cnt; i += 256)
            out[(size_t)base * 19 + i] = souts[i];
    }
}

extern "C" void kernel_launch(void* const* d_in, const int* in_sizes, int n_in,
                              void* d_out, int out_size, void* d_ws, size_t ws_size,
                              hipStream_t stream) {
    const float* cl     = (const float*)d_in[0];
    const float* cd     = (const float*)d_in[1];
    const float* re_log = (const float*)d_in[2];
    const float* mach   = (const float*)d_in[3];
    const float* alpha  = (const float*)d_in[4];
    const float* u      = (const float*)d_in[5];
    const float* We     = (const float*)d_in[6];
    const float* be     = (const float*)d_in[7];
    const float* Bmat   = (const float*)d_in[8];
    const float* Wproj  = (const float*)d_in[9];
    const float* bproj  = (const float*)d_in[10];
    const float* Wr1    = (const float*)d_in[11];
    const float* br1    = (const float*)d_in[12];
    const float* Wr2    = (const float*)d_in[13];
    const float* br2    = (const float*)d_in[14];
    const float* ln_g   = (const float*)d_in[15];
    const float* ln_b   = (const float*)d_in[16];
    const float* Wout   = (const float*)d_in[17];
    const float* bout   = (const float*)d_in[18];
    const float* fg     = (const float*)d_in[19];
    const float* fb     = (const float*)d_in[20];
    const float* Wcst   = (const float*)d_in[21];
    const float* bcst   = (const float*)d_in[22];
    const float* Wcl    = (const float*)d_in[23];
    const float* bcl    = (const float*)d_in[24];

    float* Cpre = (float*)d_ws;   // 96 floats
    const int B = in_sizes[0];

    hipLaunchKernelGGL(precompute_C_kernel, dim3(1), dim3(128), 0, stream,
                       Bmat, Wproj, bproj, Cpre);

    const int blocks = (B + 127) / 128;   // 128 rows per 256-thread block
    hipLaunchKernelGGL(whisp_kernel, dim3(blocks), dim3(256), 0, stream,
                       cl, cd, re_log, mach, alpha, u, We, be, Wproj,
                       Wr1, br1, Wr2, br2, ln_g, ln_b, Wout, bout, fg, fb,
                       Wcst, bcst, Wcl, bcl, Cpre, (float*)d_out, B);
}